// Round 4
// baseline (170.183 us; speedup 1.0000x reference)
//
#include <hip/hip_runtime.h>
#include <math.h>

// DRR via Siddon ray tracing, 256^3 volume, 256x256 detector.
// 8 threads cooperate per ray, each owning 1/8 of [amin, amax].
// Volume transposed (in d_ws) so the dominant march axis is contiguous.
// Cells are derived per-segment via midpoint-trunc, bit-faithful to the
// reference (incremental tracking diverges: fp rounding near plane 128
// snaps positions onto the plane for near-parallel rays).

#define NPLANE 256
constexpr int TPR = 8;

__device__ __forceinline__ int dominant_axis(float r0x, float r0y, float r0z) {
    float ax = fabsf(r0x), ay = fabsf(r0y), az = fabsf(r0z);
    int p = 2; float m = az;
    if (ay > m) { m = ay; p = 1; }
    if (ax > m) { m = ax; p = 0; }
    return p;
}

// alpha of plane i: (i*sp - src) * (1/sdd); numerator via fmaf (exact-cancel
// safe), then scaled. Used consistently for bounds, setup, and the merge.
__device__ __forceinline__ float palpha(int i, float sp, float src, float rd) {
    return fmaf((float)i, sp, -src) * rd;
}

// Transpose 256^3 so the dominant axis becomes contiguous.
// p==0: out[z][y][x] = in[x][y][z];  p==1: out[x][z][y] = in[x][y][z];  p==2: skip.
__global__ __launch_bounds__(256) void transpose_kernel(
    const float* __restrict__ in, float* __restrict__ out,
    const float* __restrict__ rot)
{
    float theta = rot[0], phi = rot[1];
    float ct = cosf(theta), st = sinf(theta);
    float cp = cosf(phi),   sp_ = sinf(phi);
    int p = dominant_axis(ct * cp, st * cp, -sp_);
    if (p == 2) return;

    int sA_in, sS_in, sB_out, sS_out;
    if (p == 0) { sA_in = 65536; sS_in = 256;   sB_out = 65536; sS_out = 256;   }
    else        { sA_in = 256;   sS_in = 65536; sB_out = 256;   sS_out = 65536; }

    __shared__ float tile[32][33];
    int bid   = blockIdx.x;
    int b0    = (bid & 7) * 32;
    int a0    = ((bid >> 3) & 7) * 32;
    int slice = bid >> 6;
    int lx = threadIdx.x & 31;
    int ly = threadIdx.x >> 5;

    #pragma unroll
    for (int r = 0; r < 32; r += 8)
        tile[ly + r][lx] = in[(a0 + ly + r) * sA_in + (b0 + lx) + slice * sS_in];
    __syncthreads();
    #pragma unroll
    for (int r = 0; r < 32; r += 8)
        out[(b0 + ly + r) * sB_out + (a0 + lx) + slice * sS_out] = tile[lx][ly + r];
}

__global__ __launch_bounds__(256) void drr_kernel(
    const float* __restrict__ vol,
    const float* __restrict__ vol_t,
    int use_t,
    const float* __restrict__ spacing,
    const float* __restrict__ sdrp,
    const float* __restrict__ rot,
    const float* __restrict__ trans,
    float* __restrict__ out)
{
    int gid  = blockIdx.x * blockDim.x + threadIdx.x;
    int ray  = gid >> 3;
    int part = gid & 7;
    int ti   = ray >> 8;
    int si   = ray & 255;

    float theta = rot[0], phi = rot[1], gam = rot[2];
    float ct = cosf(theta), st = sinf(theta);
    float cp = cosf(phi),   sp_ = sinf(phi);
    float cg = cosf(gam),   sg = sinf(gam);

    float r0x = ct * cp, r0y = st * cp, r0z = -sp_;
    float ux = ct * sp_ * sg - st * cg, uy = st * sp_ * sg + ct * cg, uz = cp * sg;
    float vx = ct * sp_ * cg + st * sg, vy = st * sp_ * cg - ct * sg, vz = cp * cg;

    float sdr = sdrp[0];
    float tx = trans[0], ty = trans[1], tz = trans[2];

    float sx = sdr * r0x + tx,  sy = sdr * r0y + ty,  sz = sdr * r0z + tz;
    float cxx = -sdr * r0x + tx, cxy = -sdr * r0y + ty, cxz = -sdr * r0z + tz;

    float tval = (float)(ti - 127) * 2.0f;
    float sval = (float)(si - 127) * 2.0f;

    float gx = tval * ux + sval * vx + cxx;
    float gy = tval * uy + sval * vy + cxy;
    float gz = tval * uz + sval * vz + cxz;

    float sdx = gx - sx + 1e-8f;
    float sdy = gy - sy + 1e-8f;
    float sdz = gz - sz + 1e-8f;

    float spx = spacing[0], spy = spacing[1], spz = spacing[2];

    int p = dominant_axis(r0x, r0y, r0z);
    const float* vbase; int shx, shy, shz;
    if (use_t && p == 0)      { vbase = vol_t; shx = 0;  shy = 8; shz = 16; }
    else if (use_t && p == 1) { vbase = vol_t; shx = 16; shy = 0; shz = 8;  }
    else                      { vbase = vol;   shx = 16; shy = 8; shz = 0;  }

    float rdx = 1.0f / sdx, rdy = 1.0f / sdy, rdz = 1.0f / sdz;

    float a0x = palpha(0, spx, sx, rdx), a1x = palpha(NPLANE, spx, sx, rdx);
    float a0y = palpha(0, spy, sy, rdy), a1y = palpha(NPLANE, spy, sy, rdy);
    float a0z = palpha(0, spz, sz, rdz), a1z = palpha(NPLANE, spz, sz, rdz);

    float amin = fmaxf(fmaxf(fminf(a0x, a1x), fminf(a0y, a1y)), fminf(a0z, a1z));
    float amax = fminf(fminf(fmaxf(a0x, a1x), fmaxf(a0y, a1y)), fmaxf(a0z, a1z));

    float acc = 0.f;

    if (amax > amin) {
        float range = amax - amin;
        float lo = fmaf(range, (float)part * 0.125f, amin);
        float hi = (part == TPR - 1) ? INFINITY
                                     : fmaf(range, (float)(part + 1) * 0.125f, amin);

        int ix, iy, iz, dix, diy, diz;
        float nxx, nxy, nxz;

        // first plane crossing with alpha >= lo per axis
        #define SETUP(SP, SRC, SDD, RD, I, DI, NXT)                                \
        {                                                                          \
            float q = fmaf(lo, SDD, SRC) / (SP);                                   \
            q = fminf(fmaxf(q, -1.f), 257.f);                                      \
            if ((SDD) > 0.f) {                                                     \
                DI = 1;                                                            \
                I = (int)ceilf(q);                                                 \
                while (I > 0 && palpha(I - 1, SP, SRC, RD) >= lo) --I;             \
                while (I <= NPLANE && palpha(I, SP, SRC, RD) < lo) ++I;            \
                NXT = (I <= NPLANE) ? palpha(I, SP, SRC, RD) : INFINITY;           \
            } else {                                                               \
                DI = -1;                                                           \
                I = (int)floorf(q);                                                \
                while (I < NPLANE && palpha(I + 1, SP, SRC, RD) >= lo) ++I;        \
                while (I >= 0 && palpha(I, SP, SRC, RD) < lo) --I;                 \
                NXT = (I >= 0) ? palpha(I, SP, SRC, RD) : INFINITY;                \
            }                                                                      \
        }

        SETUP(spx, sx, sdx, rdx, ix, dix, nxx)
        SETUP(spy, sy, sdy, rdy, iy, diy, nxy)
        SETUP(spz, sz, sdz, rdz, iz, diz, nxz)
        #undef SETUP

        float cur = fminf(fminf(nxx, nxy), nxz);

        float ispx = 1.0f / spx, ispy = 1.0f / spy, ispz = 1.0f / spz;

        while (cur < hi && cur < amax) {
            if (nxx == cur) { ix += dix;
                nxx = ((unsigned)ix <= NPLANE) ? palpha(ix, spx, sx, rdx) : INFINITY; }
            if (nxy == cur) { iy += diy;
                nxy = ((unsigned)iy <= NPLANE) ? palpha(iy, spy, sy, rdy) : INFINITY; }
            if (nxz == cur) { iz += diz;
                nxz = ((unsigned)iz <= NPLANE) ? palpha(iz, spz, sz, rdz) : INFINITY; }

            float nxt  = fminf(fminf(nxx, nxy), nxz);
            float e    = fminf(nxt, amax);
            float step = e - cur;

            if (step > 0.f) {
                // midpoint-trunc cells, bit-faithful to reference rounding
                float amid = 0.5f * (cur + e);
                float pxv = fmaf(amid, sdx, sx) * ispx;
                float pyv = fmaf(amid, sdy, sy) * ispy;
                float pzv = fmaf(amid, sdz, sz) * ispz;
                int jx = (int)pxv; jx = jx < 0 ? 0 : (jx > 255 ? 255 : jx);
                int jy = (int)pyv; jy = jy < 0 ? 0 : (jy > 255 ? 255 : jy);
                int jz = (int)pzv; jz = jz < 0 ? 0 : (jz > 255 ? 255 : jz);
                acc = fmaf(vbase[(jx << shx) + (jy << shy) + (jz << shz)], step, acc);
            }
            cur = nxt;
        }
    }

    for (int off = TPR / 2; off > 0; off >>= 1)
        acc += __shfl_down(acc, off, TPR);

    if (part == 0) {
        float rl = sqrtf(sdx * sdx + sdy * sdy + sdz * sdz);
        out[ray] = acc * rl;
    }
}

extern "C" void kernel_launch(void* const* d_in, const int* in_sizes, int n_in,
                              void* d_out, int out_size, void* d_ws, size_t ws_size,
                              hipStream_t stream) {
    const float* vol     = (const float*)d_in[0];
    const float* spacing = (const float*)d_in[1];
    const float* sdr     = (const float*)d_in[2];
    const float* rot     = (const float*)d_in[3];
    const float* trans   = (const float*)d_in[4];
    float* out   = (float*)d_out;
    float* vol_t = (float*)d_ws;

    int use_t = (ws_size >= (size_t)256 * 256 * 256 * 4) ? 1 : 0;

    if (use_t)
        transpose_kernel<<<16384, 256, 0, stream>>>(vol, vol_t, rot);

    int total = 256 * 256 * TPR;
    drr_kernel<<<total / 256, 256, 0, stream>>>(vol, vol_t, use_t, spacing, sdr,
                                                rot, trans, out);
}

// Round 5
// 76.634 us; speedup vs baseline: 2.2207x; 2.2207x over previous
//
#include <hip/hip_runtime.h>
#include <math.h>

// DRR via Siddon ray tracing, 256^3 volume, 256x256 detector.
// 8 threads cooperate per ray, each owning 1/8 of [amin, amax].
// Lane->ray mapping puts the detector axis with the smallest stride-weighted
// volume motion on the fast (lane) index so wave loads coalesce in the
// native x-major layout. Cells derived per-segment via midpoint-trunc
// (bit-faithful to the reference's rounding; incremental tracking diverges
// for near-plane-parallel rays).

#define NPLANE 256
constexpr int TPR = 8;

// alpha of plane i: (i*sp - src) * (1/sdd); numerator via fmaf (cancellation
// safe), then scaled by precomputed reciprocal. No IEEE divide per plane.
__device__ __forceinline__ float palpha(int i, float sp, float src, float rd) {
    return fmaf((float)i, sp, -src) * rd;
}

__global__ __launch_bounds__(256) void drr_kernel(
    const float* __restrict__ vol,
    const float* __restrict__ spacing,
    const float* __restrict__ sdrp,
    const float* __restrict__ rot,
    const float* __restrict__ trans,
    float* __restrict__ out)
{
    int gid  = blockIdx.x * blockDim.x + threadIdx.x;
    int part = gid & 7;
    int rl   = gid >> 3;            // 0..65535 linear ray id

    // R = Rz(theta) @ Ry(phi) @ Rx(gamma): columns 0 (ray dir), 1 (u), 2 (v)
    float theta = rot[0], phi = rot[1], gam = rot[2];
    float ct = cosf(theta), st = sinf(theta);
    float cp = cosf(phi),   sp_ = sinf(phi);
    float cg = cosf(gam),   sg = sinf(gam);

    float r0x = ct * cp, r0y = st * cp, r0z = -sp_;
    float ux = ct * sp_ * sg - st * cg, uy = st * sp_ * sg + ct * cg, uz = cp * sg;
    float vx = ct * sp_ * cg + st * sg, vy = st * sp_ * cg - ct * sg, vz = cp * cg;

    // choose the lane-fast detector axis: the one whose motion through the
    // volume advances the flat address least (stride-weighted). Uniform
    // across all threads -> scalar branch, no divergence. Perf-only choice.
    float cost_u = fabsf(ux) * 65536.f + fabsf(uy) * 256.f + fabsf(uz);
    float cost_v = fabsf(vx) * 65536.f + fabsf(vy) * 256.f + fabsf(vz);
    bool tfast = cost_u < cost_v;
    int ti = tfast ? (rl & 255) : (rl >> 8);
    int si = tfast ? (rl >> 8) : (rl & 255);

    float sdr = sdrp[0];
    float tx = trans[0], ty = trans[1], tz = trans[2];

    float sx = sdr * r0x + tx,  sy = sdr * r0y + ty,  sz = sdr * r0z + tz;
    float cxx = -sdr * r0x + tx, cxy = -sdr * r0y + ty, cxz = -sdr * r0z + tz;

    float tval = (float)(ti - 127) * 2.0f;
    float sval = (float)(si - 127) * 2.0f;

    float gx = tval * ux + sval * vx + cxx;
    float gy = tval * uy + sval * vy + cxy;
    float gz = tval * uz + sval * vz + cxz;

    float sdx = gx - sx + 1e-8f;
    float sdy = gy - sy + 1e-8f;
    float sdz = gz - sz + 1e-8f;

    float spx = spacing[0], spy = spacing[1], spz = spacing[2];

    float rdx = 1.0f / sdx, rdy = 1.0f / sdy, rdz = 1.0f / sdz;

    float a0x = palpha(0, spx, sx, rdx), a1x = palpha(NPLANE, spx, sx, rdx);
    float a0y = palpha(0, spy, sy, rdy), a1y = palpha(NPLANE, spy, sy, rdy);
    float a0z = palpha(0, spz, sz, rdz), a1z = palpha(NPLANE, spz, sz, rdz);

    float amin = fmaxf(fmaxf(fminf(a0x, a1x), fminf(a0y, a1y)), fminf(a0z, a1z));
    float amax = fminf(fminf(fmaxf(a0x, a1x), fmaxf(a0y, a1y)), fmaxf(a0z, a1z));

    float acc = 0.f;

    if (amax > amin) {
        float range = amax - amin;
        float lo = fmaf(range, (float)part * 0.125f, amin);
        float hi = (part == TPR - 1) ? INFINITY
                                     : fmaf(range, (float)(part + 1) * 0.125f, amin);
        float end = fminf(hi, amax);

        int ix, iy, iz, dix, diy, diz;
        float nxx, nxy, nxz;

        // first plane crossing with alpha >= lo per axis
        #define SETUP(SP, SRC, SDD, RD, I, DI, NXT)                                \
        {                                                                          \
            float q = fmaf(lo, SDD, SRC) / (SP);                                   \
            q = fminf(fmaxf(q, -1.f), 257.f);                                      \
            if ((SDD) > 0.f) {                                                     \
                DI = 1;                                                            \
                I = (int)ceilf(q);                                                 \
                while (I > 0 && palpha(I - 1, SP, SRC, RD) >= lo) --I;             \
                while (I <= NPLANE && palpha(I, SP, SRC, RD) < lo) ++I;            \
                NXT = (I <= NPLANE) ? palpha(I, SP, SRC, RD) : INFINITY;           \
            } else {                                                               \
                DI = -1;                                                           \
                I = (int)floorf(q);                                                \
                while (I < NPLANE && palpha(I + 1, SP, SRC, RD) >= lo) ++I;        \
                while (I >= 0 && palpha(I, SP, SRC, RD) < lo) --I;                 \
                NXT = (I >= 0) ? palpha(I, SP, SRC, RD) : INFINITY;                \
            }                                                                      \
        }

        SETUP(spx, sx, sdx, rdx, ix, dix, nxx)
        SETUP(spy, sy, sdy, rdy, iy, diy, nxy)
        SETUP(spz, sz, sdz, rdz, iz, diz, nxz)
        #undef SETUP

        float cur = fminf(fminf(nxx, nxy), nxz);

        float ispx = 1.0f / spx, ispy = 1.0f / spy, ispz = 1.0f / spz;

        while (cur < end) {
            if (nxx == cur) { ix += dix;
                nxx = ((unsigned)ix <= NPLANE) ? palpha(ix, spx, sx, rdx) : INFINITY; }
            if (nxy == cur) { iy += diy;
                nxy = ((unsigned)iy <= NPLANE) ? palpha(iy, spy, sy, rdy) : INFINITY; }
            if (nxz == cur) { iz += diz;
                nxz = ((unsigned)iz <= NPLANE) ? palpha(iz, spz, sz, rdz) : INFINITY; }

            float nxt  = fminf(fminf(nxx, nxy), nxz);
            float e    = fminf(nxt, amax);
            float step = e - cur;                    // >= 0 by construction

            // midpoint-trunc cells, bit-faithful to reference rounding
            float amid = 0.5f * (cur + e);
            float pxv = fmaf(amid, sdx, sx) * ispx;
            float pyv = fmaf(amid, sdy, sy) * ispy;
            float pzv = fmaf(amid, sdz, sz) * ispz;
            int jx = (int)pxv; jx = jx < 0 ? 0 : (jx > 255 ? 255 : jx);
            int jy = (int)pyv; jy = jy < 0 ? 0 : (jy > 255 ? 255 : jy);
            int jz = (int)pzv; jz = jz < 0 ? 0 : (jz > 255 ? 255 : jz);

            acc = fmaf(vol[(jx << 16) + (jy << 8) + jz], step, acc);
            cur = nxt;
        }
    }

    // combine the 8 partial integrals (lanes of one ray are contiguous)
    for (int off = TPR / 2; off > 0; off >>= 1)
        acc += __shfl_down(acc, off, TPR);

    if (part == 0) {
        float rl2 = sqrtf(sdx * sdx + sdy * sdy + sdz * sdz);
        out[ti * 256 + si] = acc * rl2;
    }
}

extern "C" void kernel_launch(void* const* d_in, const int* in_sizes, int n_in,
                              void* d_out, int out_size, void* d_ws, size_t ws_size,
                              hipStream_t stream) {
    const float* vol     = (const float*)d_in[0];
    const float* spacing = (const float*)d_in[1];
    const float* sdr     = (const float*)d_in[2];
    const float* rot     = (const float*)d_in[3];
    const float* trans   = (const float*)d_in[4];
    float* out = (float*)d_out;

    int total = 256 * 256 * TPR;   // 524288 threads
    drr_kernel<<<total / 256, 256, 0, stream>>>(vol, spacing, sdr, rot, trans, out);
}

// Round 6
// 67.387 us; speedup vs baseline: 2.5254x; 1.1372x over previous
//
#include <hip/hip_runtime.h>
#include <math.h>

// DRR via Siddon ray tracing, 256^3 volume, 256x256 detector.
// 16 threads cooperate per ray, each owning 1/16 of [amin, amax].
// Lane->ray mapping puts the detector axis with the smallest stride-weighted
// volume motion on the fast (lane) index (coalesced wave loads in the native
// x-major layout). Inner loop is software-pipelined: segment n's volume load
// is in flight while the 3-way merge advances to segment n+1.
// Cells derived per-segment via midpoint-trunc (bit-faithful to the
// reference's rounding; incremental tracking diverges for near-plane-
// parallel rays).

#define NPLANE 256
constexpr int TPR = 16;

// alpha of plane i: (i*sp - src) * (1/sdd); numerator via fmaf (cancellation
// safe), then scaled by precomputed reciprocal. No IEEE divide per plane.
__device__ __forceinline__ float palpha(int i, float sp, float src, float rd) {
    return fmaf((float)i, sp, -src) * rd;
}

__global__ __launch_bounds__(256) void drr_kernel(
    const float* __restrict__ vol,
    const float* __restrict__ spacing,
    const float* __restrict__ sdrp,
    const float* __restrict__ rot,
    const float* __restrict__ trans,
    float* __restrict__ out)
{
    int gid  = blockIdx.x * blockDim.x + threadIdx.x;
    int part = gid & (TPR - 1);
    int rl   = gid / TPR;           // 0..65535 linear ray id

    // R = Rz(theta) @ Ry(phi) @ Rx(gamma): columns 0 (ray dir), 1 (u), 2 (v)
    float theta = rot[0], phi = rot[1], gam = rot[2];
    float ct = cosf(theta), st = sinf(theta);
    float cp = cosf(phi),   sp_ = sinf(phi);
    float cg = cosf(gam),   sg = sinf(gam);

    float r0x = ct * cp, r0y = st * cp, r0z = -sp_;
    float ux = ct * sp_ * sg - st * cg, uy = st * sp_ * sg + ct * cg, uz = cp * sg;
    float vx = ct * sp_ * cg + st * sg, vy = st * sp_ * cg - ct * sg, vz = cp * cg;

    // lane-fast detector axis = least stride-weighted volume motion.
    // Wave-uniform -> scalar branch. Perf-only choice (pure permutation).
    float cost_u = fabsf(ux) * 65536.f + fabsf(uy) * 256.f + fabsf(uz);
    float cost_v = fabsf(vx) * 65536.f + fabsf(vy) * 256.f + fabsf(vz);
    bool tfast = cost_u < cost_v;
    int ti = tfast ? (rl & 255) : (rl >> 8);
    int si = tfast ? (rl >> 8) : (rl & 255);

    float sdr = sdrp[0];
    float tx = trans[0], ty = trans[1], tz = trans[2];

    float sx = sdr * r0x + tx,  sy = sdr * r0y + ty,  sz = sdr * r0z + tz;
    float cxx = -sdr * r0x + tx, cxy = -sdr * r0y + ty, cxz = -sdr * r0z + tz;

    float tval = (float)(ti - 127) * 2.0f;
    float sval = (float)(si - 127) * 2.0f;

    float gx = tval * ux + sval * vx + cxx;
    float gy = tval * uy + sval * vy + cxy;
    float gz = tval * uz + sval * vz + cxz;

    float sdx = gx - sx + 1e-8f;
    float sdy = gy - sy + 1e-8f;
    float sdz = gz - sz + 1e-8f;

    float spx = spacing[0], spy = spacing[1], spz = spacing[2];

    float rdx = 1.0f / sdx, rdy = 1.0f / sdy, rdz = 1.0f / sdz;

    float a0x = palpha(0, spx, sx, rdx), a1x = palpha(NPLANE, spx, sx, rdx);
    float a0y = palpha(0, spy, sy, rdy), a1y = palpha(NPLANE, spy, sy, rdy);
    float a0z = palpha(0, spz, sz, rdz), a1z = palpha(NPLANE, spz, sz, rdz);

    float amin = fmaxf(fmaxf(fminf(a0x, a1x), fminf(a0y, a1y)), fminf(a0z, a1z));
    float amax = fminf(fminf(fmaxf(a0x, a1x), fmaxf(a0y, a1y)), fmaxf(a0z, a1z));

    float acc = 0.f;

    if (amax > amin) {
        float range = amax - amin;
        constexpr float inv = 1.0f / (float)TPR;
        float lo = fmaf(range, (float)part * inv, amin);
        float hi = (part == TPR - 1) ? INFINITY
                                     : fmaf(range, (float)(part + 1) * inv, amin);
        float end = fminf(hi, amax);

        int ix, iy, iz, dix, diy, diz;
        float nxx, nxy, nxz;

        // first plane crossing with alpha >= lo per axis
        #define SETUP(SP, SRC, SDD, RD, I, DI, NXT)                                \
        {                                                                          \
            float q = fmaf(lo, SDD, SRC) / (SP);                                   \
            q = fminf(fmaxf(q, -1.f), 257.f);                                      \
            if ((SDD) > 0.f) {                                                     \
                DI = 1;                                                            \
                I = (int)ceilf(q);                                                 \
                while (I > 0 && palpha(I - 1, SP, SRC, RD) >= lo) --I;             \
                while (I <= NPLANE && palpha(I, SP, SRC, RD) < lo) ++I;            \
                NXT = (I <= NPLANE) ? palpha(I, SP, SRC, RD) : INFINITY;           \
            } else {                                                               \
                DI = -1;                                                           \
                I = (int)floorf(q);                                                \
                while (I < NPLANE && palpha(I + 1, SP, SRC, RD) >= lo) ++I;        \
                while (I >= 0 && palpha(I, SP, SRC, RD) < lo) --I;                 \
                NXT = (I >= 0) ? palpha(I, SP, SRC, RD) : INFINITY;                \
            }                                                                      \
        }

        SETUP(spx, sx, sdx, rdx, ix, dix, nxx)
        SETUP(spy, sy, sdy, rdy, iy, diy, nxy)
        SETUP(spz, sz, sdz, rdz, iz, diz, nxz)
        #undef SETUP

        float ispx = 1.0f / spx, ispy = 1.0f / spy, ispz = 1.0f / spz;

        #define ADVANCE_MERGE()                                                    \
            if (nxx == cur) { ix += dix;                                           \
                nxx = ((unsigned)ix <= NPLANE) ? palpha(ix, spx, sx, rdx)          \
                                               : INFINITY; }                       \
            if (nxy == cur) { iy += diy;                                           \
                nxy = ((unsigned)iy <= NPLANE) ? palpha(iy, spy, sy, rdy)          \
                                               : INFINITY; }                       \
            if (nxz == cur) { iz += diz;                                           \
                nxz = ((unsigned)iz <= NPLANE) ? palpha(iz, spz, sz, rdz)          \
                                               : INFINITY; }

        #define SEG_ADDR(CUR, E, ADDR)                                             \
        {                                                                          \
            float amid = 0.5f * ((CUR) + (E));                                     \
            float pxv = fmaf(amid, sdx, sx) * ispx;                                \
            float pyv = fmaf(amid, sdy, sy) * ispy;                                \
            float pzv = fmaf(amid, sdz, sz) * ispz;                                \
            int jx = (int)pxv; jx = jx < 0 ? 0 : (jx > 255 ? 255 : jx);            \
            int jy = (int)pyv; jy = jy < 0 ? 0 : (jy > 255 ? 255 : jy);            \
            int jz = (int)pzv; jz = jz < 0 ? 0 : (jz > 255 ? 255 : jz);            \
            ADDR = (jx << 16) + (jy << 8) + jz;                                    \
        }

        float cur = fminf(fminf(nxx, nxy), nxz);

        if (cur < end) {
            // peel: compute segment 0, issue its load
            ADVANCE_MERGE();
            float nxt = fminf(fminf(nxx, nxy), nxz);
            float e   = fminf(nxt, amax);
            int addr; SEG_ADDR(cur, e, addr)
            float pstep = e - cur;
            float pval  = vol[addr];
            cur = nxt;

            while (cur < end) {
                // advance to segment n+1 and issue its load while load n in flight
                ADVANCE_MERGE();
                nxt = fminf(fminf(nxx, nxy), nxz);
                e   = fminf(nxt, amax);
                int addr2; SEG_ADDR(cur, e, addr2)
                float nval = vol[addr2];           // issue (vmcnt grows)
                acc = fmaf(pval, pstep, acc);      // consume load n (vmcnt(1))
                pval  = nval;
                pstep = e - cur;
                cur = nxt;
            }
            acc = fmaf(pval, pstep, acc);          // drain
        }
        #undef ADVANCE_MERGE
        #undef SEG_ADDR
    }

    // combine the 16 partial integrals (lanes of one ray are contiguous)
    for (int off = TPR / 2; off > 0; off >>= 1)
        acc += __shfl_down(acc, off, TPR);

    if (part == 0) {
        float rl2 = sqrtf(sdx * sdx + sdy * sdy + sdz * sdz);
        out[ti * 256 + si] = acc * rl2;
    }
}

extern "C" void kernel_launch(void* const* d_in, const int* in_sizes, int n_in,
                              void* d_out, int out_size, void* d_ws, size_t ws_size,
                              hipStream_t stream) {
    const float* vol     = (const float*)d_in[0];
    const float* spacing = (const float*)d_in[1];
    const float* sdr     = (const float*)d_in[2];
    const float* rot     = (const float*)d_in[3];
    const float* trans   = (const float*)d_in[4];
    float* out = (float*)d_out;

    int total = 256 * 256 * TPR;   // 1,048,576 threads
    drr_kernel<<<total / 256, 256, 0, stream>>>(vol, spacing, sdr, rot, trans, out);
}